// Round 16
// baseline (1499.281 us; speedup 1.0000x reference)
//
#include <hip/hip_runtime.h>
#include <hip/hip_bf16.h>

#define BB 8
#define NTOT 8
#define NREF 7
#define CC 128
#define HW 4096
#define QQ 1024
#define EPSV 1e-12f
#define NSPLIT 8          // f32 fallback split
#define BNQ (BB * NREF * QQ)   // 57344
#define THR2E 0.012f      // 2x rigorous bf16 perturbation bound

// d_out layout (f32 words):
//   out0 [0, 4194304) ; out1 [4194304, 4202496) ; out2 [4202496, 4259840)
// Transient scratch inside out0 (overwritten later by k_cvt):
//   pairs  = out words [0, 8*BNQ*2)   (f32 fallback partials)
//   wfs_b  = bytes [4 MiB, 6 MiB)     (bf16 [b][q][c])
#define OUT1_OFF ((size_t)BB * CC * HW)
#define OUT2_OFF (OUT1_OFF + (size_t)BB * QQ)

typedef __hip_bfloat16 bf16;
typedef __attribute__((ext_vector_type(8))) short short8v;
typedef __attribute__((ext_vector_type(4))) float f32x4;

__device__ __forceinline__ float b2f(bf16 v) { return __bfloat162float(v); }
__device__ __forceinline__ float sane0(float x) {
    return (x == x && fabsf(x) < 60.f) ? x : 0.f;
}
__device__ __forceinline__ float ldv(const void* p, size_t i, int f32) {
    return f32 ? ((const float*)p)[i] : b2f(((const bf16*)p)[i]);
}
__device__ __forceinline__ ushort f2bs(float x) {
    bf16 t = __float2bfloat16(x);
    return *(ushort*)&t;
}

// ---------------------------------------------------------------------------
// K0: detect per-tensor device dtype (f32 vs bf16). (Working since R8.)
__global__ void k_detect(const void* __restrict__ feat, const void* __restrict__ refs,
                         const void* __restrict__ sim, int* __restrict__ flags) {
    if (threadIdx.x == 0) {
        const ushort* p = (const ushort*)feat;
        int c1 = 0;
        for (int i = 0; i < 256; i++) {
            float v = b2f(*(const bf16*)&p[(size_t)i * 16384]);
            if (!(fabsf(v) <= 100.f)) c1++;
        }
        flags[0] = c1 > 32 ? 1 : 0;
        p = (const ushort*)refs; c1 = 0;
        for (int i = 0; i < 256; i++) {
            float v = b2f(*(const bf16*)&p[(size_t)i * 131072]);
            if (!(fabsf(v) <= 100.f)) c1++;
        }
        flags[1] = c1 > 32 ? 1 : 0;
        p = (const ushort*)sim; c1 = 0;
        for (int i = 0; i < 32; i++) {
            float v = b2f(*(const bf16*)&p[i * 2]);
            if (!(fabsf(v) <= 100.f)) c1++;
        }
        flags[2] = c1 > 4 ? 1 : 0;
    }
}

// ---------------------------------------------------------------------------
// K0b: verify the assumed MFMA fragment layout (exact-integer patterns).
__global__ void k_probe(int* __restrict__ flags) {
    int l = threadIdx.x;   // one wave
    int lo = l & 15, hi = l >> 4;
    short8v a, b;
    #pragma unroll
    for (int j = 0; j < 8; j++) {
        int k = hi * 8 + j;
        a[j] = (short)f2bs((float)(((lo * 31 + k * 7) % 13) - 6));
        b[j] = (short)f2bs((float)(((k * 5 + lo * 11) % 11) - 5));
    }
    f32x4 acc = {0.f, 0.f, 0.f, 0.f};
    acc = __builtin_amdgcn_mfma_f32_16x16x32_bf16(a, b, acc, 0, 0, 0);
    bool ok = true;
    #pragma unroll
    for (int reg = 0; reg < 4; reg++) {
        int row = hi * 4 + reg, col = lo;
        float ref = 0.f;
        for (int k = 0; k < 32; k++)
            ref += (float)(((row * 31 + k * 7) % 13) - 6) *
                   (float)(((k * 5 + col * 11) % 11) - 5);
        if (acc[reg] != ref) ok = false;
    }
    unsigned long long m = __ballot(ok);
    if (l == 0) flags[3] = (m == ~0ull) ? 1 : 0;
}

// ---------------------------------------------------------------------------
// K1: wfs columns; writes f32 wfs_t[b][c][q] AND bf16 wfs_b[b][q][c].
__global__ void k_wfs(const void* __restrict__ feat, const int* __restrict__ fidx,
                      const int* __restrict__ flags, float* __restrict__ wfs_t,
                      ushort* __restrict__ wfs_b) {
    int ff = flags[0];
    int bq = blockIdx.x;
    int b = bq >> 10;
    int q = bq & 1023;
    int idx = fidx[b * QQ + q] & (HW - 1);
    int l = threadIdx.x;  // 0..63
    size_t base = (size_t)b * CC * HW + idx;
    float x0 = ldv(feat, base + (size_t)l * HW, ff);
    float x1 = ldv(feat, base + (size_t)(l + 64) * HW, ff);
    float s = x0 * x0 + x1 * x1;
    #pragma unroll
    for (int m = 1; m < 64; m <<= 1) s += __shfl_xor(s, m, 64);
    float d1 = fmaxf(sqrtf(s), EPSV);
    float y0 = x0 / d1, y1 = x1 / d1;
    float s2 = y0 * y0 + y1 * y1;
    #pragma unroll
    for (int m = 1; m < 64; m <<= 1) s2 += __shfl_xor(s2, m, 64);
    float d2 = fmaxf(sqrtf(s2), EPSV);
    float w0 = y0 / d2, w1 = y1 / d2;
    wfs_t[((size_t)(b * CC + l)) * QQ + q] = w0;
    wfs_t[((size_t)(b * CC + l + 64)) * QQ + q] = w1;
    ushort* wb = wfs_b + ((size_t)(b * QQ) + q) * CC;
    wb[l] = f2bs(w0);
    wb[l + 64] = f2bs(w1);
}

// ---------------------------------------------------------------------------
// K2: rinv[b][n][k] = 1 / max(||refs col||, eps)
__global__ void k_rnorm(const void* __restrict__ refs, const int* __restrict__ pindex,
                        const int* __restrict__ flags, float* __restrict__ rinv) {
    int rf = flags[1];
    int gb = blockIdx.x;
    int kc = gb & 15;
    int bn = gb >> 4;
    int n = bn % NREF;
    int b = bn / NREF;
    int index = *pindex & 7;
    int kn = n < index ? n : n + 1;
    int k = kc * 256 + threadIdx.x;
    size_t base = (size_t)(b * NTOT + kn) * CC * HW + k;
    float s = 0.f;
    #pragma unroll 4
    for (int c = 0; c < CC; c++) {
        float x = ldv(refs, base + (size_t)c * HW, rf);
        s = fmaf(x, x, s);
    }
    rinv[(b * NREF + n) * HW + k] = 1.0f / fmaxf(sqrtf(s), EPSV);
}

// ---------------------------------------------------------------------------
// K3-MFMA (filter+verify): block = (b,n, 64 q). Pass 1: MFMA approx scores ->
// per-query max m-hat. Pass 2: identical recompute; candidates (shat >= m-hat
// - 2eps) get EXACT f32 dot; exact max with min-k tie -> out2. Provably equals
// the exact argmax (eps = rigorous bf16 perturbation bound 0.006; 2eps=0.012).
__global__ __launch_bounds__(256) void k_amax_mfma(
        const void* __restrict__ refs, const ushort* __restrict__ wfs_b,
        const float* __restrict__ wfs_t, const float* __restrict__ rinv,
        const int* __restrict__ pindex, const int* __restrict__ flags,
        float* __restrict__ out2) {
    __shared__ ushort lr[64 * 128];  // 16 KiB
    if (!flags[3]) return;
    int rf = flags[1];
    int gb = blockIdx.x;            // 16 qtiles * 56 bn = 896
    int qtile = gb & 15;
    int bn = gb >> 4;
    int n = bn % NREF;
    int b = bn / NREF;
    int index = *pindex & 7;
    int kn = n < index ? n : n + 1;
    int q0 = qtile * 64;
    int t = threadIdx.x;
    int w = t >> 6, l = t & 63;
    int lo = l & 15, hi = l >> 4;
    int myq = q0 + w * 16 + lo;

    size_t rbase = (size_t)(b * NTOT + kn) * CC * HW;
    const float* rib = rinv + (b * NREF + n) * HW;

    // B-frags (wfs bf16) in registers; element j of bfr[cc] is c = cc*32+hi*8+j
    short8v bfr[4];
    const ushort* wb = wfs_b + ((size_t)(b * QQ) + myq) * CC;
    #pragma unroll
    for (int cc = 0; cc < 4; cc++)
        bfr[cc] = *(const short8v*)&wb[cc * 32 + hi * 8];

    int x0t = (t & 15) * 4;   // staged k-quad
    int cs = t >> 4;          // c-octet row

    // ---------------- pass 1: m-hat ----------------
    float mhat = -3.402823466e38f;
    for (int tile = 0; tile < 64; tile++) {
        int k0 = tile * 64;
        __syncthreads();
        ushort4 u[8];
        if (rf) {
            #pragma unroll
            for (int s = 0; s < 8; s++) {
                float4 v = *(const float4*)&((const float*)refs)
                        [rbase + (size_t)(cs * 8 + s) * HW + k0 + x0t];
                ushort4 o;
                o.x = f2bs(v.x); o.y = f2bs(v.y); o.z = f2bs(v.z); o.w = f2bs(v.w);
                u[s] = o;
            }
        } else {
            #pragma unroll
            for (int s = 0; s < 8; s++)
                u[s] = *(const ushort4*)&((const ushort*)refs)
                        [rbase + (size_t)(cs * 8 + s) * HW + k0 + x0t];
        }
        #pragma unroll
        for (int i = 0; i < 4; i++) {
            int k = x0t + i;
            short8v wv;
            #pragma unroll
            for (int s = 0; s < 8; s++) wv[s] = (short)((const ushort*)&u[s])[i];
            *(short8v*)&lr[k * 128 + ((cs * 8) ^ ((k & 15) << 3))] = wv;
        }
        __syncthreads();

        #pragma unroll
        for (int sub = 0; sub < 4; sub++) {
            f32x4 acc = {0.f, 0.f, 0.f, 0.f};
            int krow = sub * 16 + lo;
            #pragma unroll
            for (int cc = 0; cc < 4; cc++) {
                short8v afr = *(const short8v*)
                    &lr[krow * 128 + ((cc * 32 + hi * 8) ^ ((krow & 15) << 3))];
                acc = __builtin_amdgcn_mfma_f32_16x16x32_bf16(afr, bfr[cc], acc, 0, 0, 0);
            }
            float4 ri = *(const float4*)&rib[k0 + sub * 16 + hi * 4];
            const float rr[4] = {ri.x, ri.y, ri.z, ri.w};
            #pragma unroll
            for (int reg = 0; reg < 4; reg++)
                mhat = fmaxf(mhat, acc[reg] * rr[reg]);
        }
    }
    // per-query max across the 4 hi-groups (all lanes converge)
    #pragma unroll
    for (int m = 16; m < 64; m <<= 1)
        mhat = fmaxf(mhat, __shfl_xor(mhat, m, 64));
    float thr = mhat - THR2E;

    // ---------------- pass 2: candidates -> exact ----------------
    float bs = -3.402823466e38f;
    int bk = 0;
    const float* wcol = wfs_t + (size_t)b * CC * QQ + myq;
    for (int tile = 0; tile < 64; tile++) {
        int k0 = tile * 64;
        __syncthreads();
        ushort4 u[8];
        if (rf) {
            #pragma unroll
            for (int s = 0; s < 8; s++) {
                float4 v = *(const float4*)&((const float*)refs)
                        [rbase + (size_t)(cs * 8 + s) * HW + k0 + x0t];
                ushort4 o;
                o.x = f2bs(v.x); o.y = f2bs(v.y); o.z = f2bs(v.z); o.w = f2bs(v.w);
                u[s] = o;
            }
        } else {
            #pragma unroll
            for (int s = 0; s < 8; s++)
                u[s] = *(const ushort4*)&((const ushort*)refs)
                        [rbase + (size_t)(cs * 8 + s) * HW + k0 + x0t];
        }
        #pragma unroll
        for (int i = 0; i < 4; i++) {
            int k = x0t + i;
            short8v wv;
            #pragma unroll
            for (int s = 0; s < 8; s++) wv[s] = (short)((const ushort*)&u[s])[i];
            *(short8v*)&lr[k * 128 + ((cs * 8) ^ ((k & 15) << 3))] = wv;
        }
        __syncthreads();

        #pragma unroll
        for (int sub = 0; sub < 4; sub++) {
            f32x4 acc = {0.f, 0.f, 0.f, 0.f};
            int krow = sub * 16 + lo;
            #pragma unroll
            for (int cc = 0; cc < 4; cc++) {
                short8v afr = *(const short8v*)
                    &lr[krow * 128 + ((cc * 32 + hi * 8) ^ ((krow & 15) << 3))];
                acc = __builtin_amdgcn_mfma_f32_16x16x32_bf16(afr, bfr[cc], acc, 0, 0, 0);
            }
            float4 ri = *(const float4*)&rib[k0 + sub * 16 + hi * 4];
            const float rr[4] = {ri.x, ri.y, ri.z, ri.w};
            #pragma unroll
            for (int reg = 0; reg < 4; reg++) {
                float v = acc[reg] * rr[reg];
                if (v >= thr) {
                    int gk = k0 + sub * 16 + hi * 4 + reg;
                    float s_ex = 0.f;
                    #pragma unroll 4
                    for (int c = 0; c < CC; c++)
                        s_ex = fmaf(wcol[(size_t)c * QQ],
                                    ldv(refs, rbase + (size_t)c * HW + gk, rf), s_ex);
                    s_ex *= rib[gk];
                    if (s_ex > bs || (s_ex == bs && gk < bk)) { bs = s_ex; bk = gk; }
                }
            }
        }
    }

    // reduce exact (bs,bk) across hi-groups, min-k ties
    #pragma unroll
    for (int m = 16; m < 64; m <<= 1) {
        float vo = __shfl_xor(bs, m, 64);
        int io = __shfl_xor(bk, m, 64);
        if (vo > bs || (vo == bs && io < bk)) { bs = vo; bk = io; }
    }
    if (hi == 0)
        out2[(size_t)(b * NREF + n) * QQ + myq] = (float)bk;
}

// ---------------------------------------------------------------------------
// K3-F32 (R14 fallback; runs only if the MFMA layout probe failed)
__global__ __launch_bounds__(256, 4) void k_argmax(
        const void* __restrict__ refs, const float* __restrict__ wfs_t,
        const float* __restrict__ rinv, const int* __restrict__ pindex,
        const int* __restrict__ flags, float2* __restrict__ pairs) {
    __shared__ __align__(16) float lw[32][128];
    __shared__ __align__(16) float lr2[32][128];
    if (flags[3]) return;
    int rf = flags[1];
    int gb = blockIdx.x;
    int qtile = gb & 7;
    int r = gb >> 3;
    int bn = r % 56;
    int ks = r / 56;
    int n = bn % NREF;
    int b = bn / NREF;
    int index = *pindex & 7;
    int kn = n < index ? n : n + 1;
    int q0 = qtile * 128;
    int kbase = ks * (HW / NSPLIT);
    int t = threadIdx.x;
    int qt = t >> 4, kt = t & 15;

    const float* wsrc = wfs_t + (size_t)b * CC * QQ + q0;
    size_t rbase = (size_t)(b * NTOT + kn) * CC * HW;
    const float* rib = rinv + (b * NREF + n) * HW;

    float best[8];
    int bidx[8];
    #pragma unroll
    for (int j = 0; j < 8; j++) { best[j] = -3.402823466e38f; bidx[j] = 0; }

    int x0 = (t & 31) * 4;
    int cb = t >> 5;

    for (int kt0 = 0; kt0 < HW / NSPLIT; kt0 += 128) {
        int k0 = kbase + kt0;
        float acc[8][8];
        #pragma unroll
        for (int j = 0; j < 8; j++)
            #pragma unroll
            for (int i = 0; i < 8; i++) acc[j][i] = 0.f;

        float4 ri4 = *(const float4*)&rib[k0 + x0];

        for (int cc0 = 0; cc0 < CC; cc0 += 32) {
            __syncthreads();
            #pragma unroll
            for (int i = 0; i < 4; i++) {
                int flat4 = i * 1024 + t * 4;
                int c = flat4 >> 7, x = flat4 & 127;
                *(float4*)&lw[c][x] =
                    *(const float4*)&wsrc[(size_t)(cc0 + c) * QQ + x];
            }
            #pragma unroll
            for (int s = 0; s < 4; s++) {
                int c = cb + s * 8;
                float4 v;
                if (rf) {
                    v = *(const float4*)&((const float*)refs)
                            [rbase + (size_t)(cc0 + c) * HW + k0 + x0];
                } else {
                    ushort4 uu = *(const ushort4*)&((const ushort*)refs)
                            [rbase + (size_t)(cc0 + c) * HW + k0 + x0];
                    v.x = b2f(*(const bf16*)&uu.x); v.y = b2f(*(const bf16*)&uu.y);
                    v.z = b2f(*(const bf16*)&uu.z); v.w = b2f(*(const bf16*)&uu.w);
                }
                v.x *= ri4.x; v.y *= ri4.y; v.z *= ri4.z; v.w *= ri4.w;
                *(float4*)&lr2[c][x0] = v;
            }
            __syncthreads();

            #pragma unroll 4
            for (int c = 0; c < 32; c++) {
                const float4 wq0 = *(const float4*)&lw[c][qt * 8];
                const float4 wq1 = *(const float4*)&lw[c][qt * 8 + 4];
                const float4 rk0 = *(const float4*)&lr2[c][kt * 4];
                const float4 rk1 = *(const float4*)&lr2[c][64 + kt * 4];
                const float wq[8] = {wq0.x, wq0.y, wq0.z, wq0.w,
                                     wq1.x, wq1.y, wq1.z, wq1.w};
                const float rk[8] = {rk0.x, rk0.y, rk0.z, rk0.w,
                                     rk1.x, rk1.y, rk1.z, rk1.w};
                #pragma unroll
                for (int j = 0; j < 8; j++)
                    #pragma unroll
                    for (int i = 0; i < 8; i++)
                        acc[j][i] = fmaf(wq[j], rk[i], acc[j][i]);
            }
        }

        #pragma unroll
        for (int j = 0; j < 8; j++) {
            #pragma unroll
            for (int i = 0; i < 8; i++) {
                float v = acc[j][i];
                int gk = k0 + (i < 4 ? kt * 4 + i : 64 + kt * 4 + (i - 4));
                if (v > best[j]) { best[j] = v; bidx[j] = gk; }
            }
        }
    }

    #pragma unroll
    for (int j = 0; j < 8; j++) {
        float v = best[j];
        int i = bidx[j];
        #pragma unroll
        for (int m = 1; m < 16; m <<= 1) {
            float vo = __shfl_xor(v, m, 64);
            int io = __shfl_xor(i, m, 64);
            if (vo > v || (vo == v && io < i)) { v = vo; i = io; }
        }
        if (kt == 0) {
            float2 pr; pr.x = v; pr.y = (float)i;
            pairs[(size_t)ks * BNQ + (size_t)(b * NREF + n) * QQ + q0 + qt * 8 + j] = pr;
        }
    }
}

// K3b: fold fallback partials (only in f32-fallback mode)
__global__ void k_amax2(const float2* __restrict__ pairs, const int* __restrict__ flags,
                        float* __restrict__ out2) {
    if (flags[3]) return;   // MFMA path wrote out2 directly
    int j = blockIdx.x * 256 + threadIdx.x;
    float2 best = pairs[j];
    for (int s = 1; s < NSPLIT; s++) {
        float2 p = pairs[(size_t)s * BNQ + j];
        if (p.x > best.x) best = p;
    }
    out2[j] = best.y;
}

// ---------------------------------------------------------------------------
// K4a: out0 background = f32(feat), dtype-aware, scrubbed.
__global__ void k_cvt(const void* __restrict__ feat, const int* __restrict__ flags,
                      float* __restrict__ dst) {
    int ff = flags[0];
    size_t i4 = (size_t)blockIdx.x * 256 + threadIdx.x;
    float4 o;
    if (ff) {
        o = ((const float4*)feat)[i4];
    } else {
        ushort4 v = ((const ushort4*)feat)[i4];
        o.x = b2f(*(const bf16*)&v.x); o.y = b2f(*(const bf16*)&v.y);
        o.z = b2f(*(const bf16*)&v.z); o.w = b2f(*(const bf16*)&v.w);
    }
    o.x = sane0(o.x); o.y = sane0(o.y); o.z = sane0(o.z); o.w = sane0(o.w);
    ((float4*)dst)[i4] = o;
}

__global__ void k_aux(const int* __restrict__ fidx, float* __restrict__ out) {
    int j = blockIdx.x * 256 + threadIdx.x;
    float r = b2f(__float2bfloat16((float)fidx[j]));
    out[OUT1_OFF + j] = (r == r) ? r : 0.f;
}

__global__ void k_fuse(const void* __restrict__ feat, const void* __restrict__ refs,
                       const void* __restrict__ sim, const int* __restrict__ fidx,
                       const int* __restrict__ pindex, const int* __restrict__ flags,
                       float* __restrict__ out) {
    int ff = flags[0], rf = flags[1], sf = flags[2];
    int bq = blockIdx.x;
    int b = bq >> 10;
    int q = bq & 1023;
    int c = threadIdx.x;
    int index = *pindex & 7;
    int idx = fidx[b * QQ + q] & (HW - 1);
    float base = ldv(sim, b * NTOT + index, sf);
    float f = ldv(feat, ((size_t)(b * CC) + c) * HW + idx, ff);
    float s = 0.f;
    const float* ridxf = out + OUT2_OFF;
    #pragma unroll
    for (int n = 0; n < NREF; n++) {
        int kn = n < index ? n : n + 1;
        float sn = ldv(sim, b * NTOT + kn, sf);
        int rk = (int)ridxf[(size_t)(b * NREF + n) * QQ + q] & (HW - 1);
        float rv = ldv(refs, ((size_t)((b * NTOT + kn) * CC) + c) * HW + rk, rf);
        s = fmaf(sn, rv, s);
    }
    out[((size_t)(b * CC) + c) * HW + idx] = sane0(base * f + s);
}

__global__ void k_round(float* __restrict__ out) {
    int j = blockIdx.x * 256 + threadIdx.x;
    float v = out[OUT2_OFF + j];
    float r = b2f(__float2bfloat16(v));
    out[OUT2_OFF + j] = (r == r && fabsf(r) < 1e6f) ? r : 0.f;
}

// ---------------------------------------------------------------------------
extern "C" void kernel_launch(void* const* d_in, const int* in_sizes, int n_in,
                              void* d_out, int out_size, void* d_ws, size_t ws_size,
                              hipStream_t stream) {
    const void* feat = 0; const void* refs = 0; const void* sim = 0;
    const int* fidx = 0; const int* pindex = 0;
    for (int i = 0; i < n_in; i++) {
        switch (in_sizes[i]) {
            case BB * CC * HW:        feat = d_in[i]; break;
            case BB * NTOT * CC * HW: refs = d_in[i]; break;
            case BB * NTOT:           sim = d_in[i]; break;
            case BB * QQ:             fidx = (const int*)d_in[i]; break;
            case 1:                   pindex = (const int*)d_in[i]; break;
        }
    }
    float* out = (float*)d_out;
    char* ws = (char*)d_ws;
    int* flags = (int*)ws;                                         // 4 ints
    float* wfs_t = (float*)(ws + 256);                             // 4 MiB
    float* rinv = (float*)(ws + 256 + (size_t)BB * CC * QQ * 4);   // 896 KiB
    float2* pairs = (float2*)out;                                  // fallback scratch
    ushort* wfs_b = (ushort*)((char*)out + (size_t)4 * 1024 * 1024);  // 2 MiB
    float* out2 = out + OUT2_OFF;

    k_detect<<<1, 64, 0, stream>>>(feat, refs, sim, flags);
    k_probe<<<1, 64, 0, stream>>>(flags);
    k_wfs<<<BB * QQ, 64, 0, stream>>>(feat, fidx, flags, wfs_t, wfs_b);
    k_rnorm<<<BB * NREF * (HW / 256), 256, 0, stream>>>(refs, pindex, flags, rinv);
    k_amax_mfma<<<BB * NREF * 16, 256, 0, stream>>>(refs, wfs_b, wfs_t, rinv, pindex, flags, out2);
    k_argmax<<<NSPLIT * BB * NREF * 8, 256, 0, stream>>>(refs, wfs_t, rinv, pindex, flags, pairs);
    k_amax2<<<BNQ / 256, 256, 0, stream>>>(pairs, flags, out2);
    k_cvt<<<(BB * CC * HW / 4) / 256, 256, 0, stream>>>(feat, flags, out);
    k_aux<<<(BB * QQ) / 256, 256, 0, stream>>>(fidx, out);
    k_fuse<<<BB * QQ, 128, 0, stream>>>(feat, refs, sim, fidx, pindex, flags, out);
    k_round<<<(BB * NREF * QQ) / 256, 256, 0, stream>>>(out);
}

// Round 17
// 1047.221 us; speedup vs baseline: 1.4317x; 1.4317x over previous
//
#include <hip/hip_runtime.h>
#include <hip/hip_bf16.h>

#define BB 8
#define NTOT 8
#define NREF 7
#define CC 128
#define HW 4096
#define QQ 1024
#define EPSV 1e-12f
#define NSPLIT 16
#define BNQ (BB * NREF * QQ)   // 57344

// d_out layout (f32 words):
//   out0 [0, 4194304)       : fused feature map (b,c,hw)
//   out1 [4194304, 4202496) : feat_indices (bf16-rounded f32)
//   out2 [4202496, 4259840) : ref_idx (exact ints until k_round quantizes)
// Transient scratch inside out0 (overwritten later by k_cvt):
//   pairs = out words [0, NSPLIT*BNQ*2)  (7.3 MiB)
#define OUT1_OFF ((size_t)BB * CC * HW)
#define OUT2_OFF (OUT1_OFF + (size_t)BB * QQ)

typedef __hip_bfloat16 bf16;

__device__ __forceinline__ float b2f(bf16 v) { return __bfloat162float(v); }
__device__ __forceinline__ float sane0(float x) {
    return (x == x && fabsf(x) < 60.f) ? x : 0.f;
}
// dtype-flag-aware load: element i of a logically-float tensor
__device__ __forceinline__ float ldv(const void* p, size_t i, int f32) {
    return f32 ? ((const float*)p)[i] : b2f(((const bf16*)p)[i]);
}

// ---------------------------------------------------------------------------
// K0: detect per-tensor device dtype (f32 vs bf16). (Working since R8.)
__global__ void k_detect(const void* __restrict__ feat, const void* __restrict__ refs,
                         const void* __restrict__ sim, int* __restrict__ flags) {
    if (threadIdx.x == 0) {
        const ushort* p = (const ushort*)feat;
        int c1 = 0;
        for (int i = 0; i < 256; i++) {
            float v = b2f(*(const bf16*)&p[(size_t)i * 16384]);  // even idx
            if (!(fabsf(v) <= 100.f)) c1++;
        }
        flags[0] = c1 > 32 ? 1 : 0;
        p = (const ushort*)refs; c1 = 0;
        for (int i = 0; i < 256; i++) {
            float v = b2f(*(const bf16*)&p[(size_t)i * 131072]);
            if (!(fabsf(v) <= 100.f)) c1++;
        }
        flags[1] = c1 > 32 ? 1 : 0;
        p = (const ushort*)sim; c1 = 0;
        for (int i = 0; i < 32; i++) {
            float v = b2f(*(const bf16*)&p[i * 2]);
            if (!(fabsf(v) <= 100.f)) c1++;
        }
        flags[2] = c1 > 4 ? 1 : 0;
    }
}

// ---------------------------------------------------------------------------
// K1: per (b,q) selected feat column: l2norm over c twice -> wfs_t[b][c][q].
__global__ void k_wfs(const void* __restrict__ feat, const int* __restrict__ fidx,
                      const int* __restrict__ flags, float* __restrict__ wfs_t) {
    int ff = flags[0];
    int bq = blockIdx.x;
    int b = bq >> 10;
    int q = bq & 1023;
    int idx = fidx[b * QQ + q] & (HW - 1);
    int l = threadIdx.x;  // 0..63
    size_t base = (size_t)b * CC * HW + idx;
    float x0 = ldv(feat, base + (size_t)l * HW, ff);
    float x1 = ldv(feat, base + (size_t)(l + 64) * HW, ff);
    float s = x0 * x0 + x1 * x1;
    #pragma unroll
    for (int m = 1; m < 64; m <<= 1) s += __shfl_xor(s, m, 64);
    float d1 = fmaxf(sqrtf(s), EPSV);
    float y0 = x0 / d1, y1 = x1 / d1;
    float s2 = y0 * y0 + y1 * y1;
    #pragma unroll
    for (int m = 1; m < 64; m <<= 1) s2 += __shfl_xor(s2, m, 64);
    float d2 = fmaxf(sqrtf(s2), EPSV);
    wfs_t[((size_t)(b * CC + l)) * QQ + q] = y0 / d2;
    wfs_t[((size_t)(b * CC + l + 64)) * QQ + q] = y1 / d2;
}

// ---------------------------------------------------------------------------
// K2: rinv[b][n][k] = 1 / max(||refs col||, eps)   (one IEEE div)
__global__ void k_rnorm(const void* __restrict__ refs, const int* __restrict__ pindex,
                        const int* __restrict__ flags, float* __restrict__ rinv) {
    int rf = flags[1];
    int gb = blockIdx.x;           // B*NREF*16
    int kc = gb & 15;
    int bn = gb >> 4;
    int n = bn % NREF;
    int b = bn / NREF;
    int index = *pindex & 7;
    int kn = n < index ? n : n + 1;
    int k = kc * 256 + threadIdx.x;
    size_t base = (size_t)(b * NTOT + kn) * CC * HW + k;
    float s = 0.f;
    #pragma unroll 4
    for (int c = 0; c < CC; c++) {
        float x = ldv(refs, base + (size_t)c * HW, rf);
        s = fmaf(x, x, s);
    }
    rinv[(b * NREF + n) * HW + k] = 1.0f / fmaxf(sqrtf(s), EPSV);
}

// ---------------------------------------------------------------------------
// K3 (R14 structure, NSPLIT=16): 8q x 8k micro-tile, vector staging, rinv mul,
// no divides in the hot loop. Identical per-(q,k) arithmetic chain as R12/R14.
__global__ __launch_bounds__(256, 4) void k_argmax(
        const void* __restrict__ refs, const float* __restrict__ wfs_t,
        const float* __restrict__ rinv, const int* __restrict__ pindex,
        const int* __restrict__ flags, float2* __restrict__ pairs) {
    __shared__ __align__(16) float lw[32][128];  // [c][q] 16 KiB
    __shared__ __align__(16) float lr[32][128];  // [c][k] 16 KiB
    int rf = flags[1];
    int gb = blockIdx.x;           // NSPLIT * 448
    int qtile = gb & 7;
    int r = gb >> 3;               // 0..NSPLIT*56-1
    int bn = r % 56;
    int ks = r / 56;
    int n = bn % NREF;
    int b = bn / NREF;
    int index = *pindex & 7;
    int kn = n < index ? n : n + 1;
    int q0 = qtile * 128;
    int kbase = ks * (HW / NSPLIT);
    int t = threadIdx.x;
    int qt = t >> 4, kt = t & 15;

    const float* wsrc = wfs_t + (size_t)b * CC * QQ + q0;
    size_t rbase = (size_t)(b * NTOT + kn) * CC * HW;
    const float* rib = rinv + (b * NREF + n) * HW;

    float best[8];
    int bidx[8];
    #pragma unroll
    for (int j = 0; j < 8; j++) { best[j] = -3.402823466e38f; bidx[j] = 0; }

    int x0 = (t & 31) * 4;    // staged k-quad within the 128-k tile
    int cb = t >> 5;          // 0..7

    for (int kt0 = 0; kt0 < HW / NSPLIT; kt0 += 128) {   // 2 k-tiles
        int k0 = kbase + kt0;
        float acc[8][8];
        #pragma unroll
        for (int j = 0; j < 8; j++)
            #pragma unroll
            for (int i = 0; i < 8; i++) acc[j][i] = 0.f;

        float4 ri4 = *(const float4*)&rib[k0 + x0];

        for (int cc0 = 0; cc0 < CC; cc0 += 32) {  // 4 c-chunks, ascending
            __syncthreads();  // previous phase's reads done
            // stage lw: 16 f32/thread, vectorized
            #pragma unroll
            for (int i = 0; i < 4; i++) {
                int flat4 = i * 1024 + t * 4;
                int c = flat4 >> 7, x = flat4 & 127;
                *(float4*)&lw[c][x] =
                    *(const float4*)&wsrc[(size_t)(cc0 + c) * QQ + x];
            }
            // stage lr: 4 k-quads x 4 c-rows per thread, scaled by rinv
            #pragma unroll
            for (int s = 0; s < 4; s++) {
                int c = cb + s * 8;      // 0..31
                float4 v;
                if (rf) {
                    v = *(const float4*)&((const float*)refs)
                            [rbase + (size_t)(cc0 + c) * HW + k0 + x0];
                } else {
                    ushort4 u = *(const ushort4*)&((const ushort*)refs)
                            [rbase + (size_t)(cc0 + c) * HW + k0 + x0];
                    v.x = b2f(*(const bf16*)&u.x); v.y = b2f(*(const bf16*)&u.y);
                    v.z = b2f(*(const bf16*)&u.z); v.w = b2f(*(const bf16*)&u.w);
                }
                v.x *= ri4.x; v.y *= ri4.y; v.z *= ri4.z; v.w *= ri4.w;
                *(float4*)&lr[c][x0] = v;
            }
            __syncthreads();

            #pragma unroll 4
            for (int c = 0; c < 32; c++) {
                const float4 wq0 = *(const float4*)&lw[c][qt * 8];
                const float4 wq1 = *(const float4*)&lw[c][qt * 8 + 4];
                const float4 rk0 = *(const float4*)&lr[c][kt * 4];
                const float4 rk1 = *(const float4*)&lr[c][64 + kt * 4];
                const float wq[8] = {wq0.x, wq0.y, wq0.z, wq0.w,
                                     wq1.x, wq1.y, wq1.z, wq1.w};
                const float rk[8] = {rk0.x, rk0.y, rk0.z, rk0.w,
                                     rk1.x, rk1.y, rk1.z, rk1.w};
                #pragma unroll
                for (int j = 0; j < 8; j++)
                    #pragma unroll
                    for (int i = 0; i < 8; i++)
                        acc[j][i] = fmaf(wq[j], rk[i], acc[j][i]);
            }
        }

        // fold this tile (ascending k order preserved)
        #pragma unroll
        for (int j = 0; j < 8; j++) {
            #pragma unroll
            for (int i = 0; i < 8; i++) {
                float v = acc[j][i];
                int gk = k0 + (i < 4 ? kt * 4 + i : 64 + kt * 4 + (i - 4));
                if (v > best[j]) { best[j] = v; bidx[j] = gk; }
            }
        }
    }

    // reduce across the 16 kt-lanes (xor 1,2,4,8 stays in the 16-lane group)
    #pragma unroll
    for (int j = 0; j < 8; j++) {
        float v = best[j];
        int i = bidx[j];
        #pragma unroll
        for (int m = 1; m < 16; m <<= 1) {
            float vo = __shfl_xor(v, m, 64);
            int io = __shfl_xor(i, m, 64);
            if (vo > v || (vo == v && io < i)) { v = vo; i = io; }
        }
        if (kt == 0) {
            float2 pr; pr.x = v; pr.y = (float)i;
            pairs[(size_t)ks * BNQ + (size_t)(b * NREF + n) * QQ + q0 + qt * 8 + j] = pr;
        }
    }
}

// K3b: fold the NSPLIT partials (ascending split order keeps first-index ties)
__global__ void k_amax2(const float2* __restrict__ pairs, float* __restrict__ out2) {
    int j = blockIdx.x * 256 + threadIdx.x;  // 0..BNQ-1
    float2 best = pairs[j];
    #pragma unroll
    for (int s = 1; s < NSPLIT; s++) {
        float2 p = pairs[(size_t)s * BNQ + j];
        if (p.x > best.x) best = p;
    }
    out2[j] = best.y;
}

// ---------------------------------------------------------------------------
// K4a: out0 background = f32(feat), dtype-aware, scrubbed. Runs AFTER k_amax2
// (overwrites the pairs scratch living at the start of out0).
__global__ void k_cvt(const void* __restrict__ feat, const int* __restrict__ flags,
                      float* __restrict__ dst) {
    int ff = flags[0];
    size_t i4 = (size_t)blockIdx.x * 256 + threadIdx.x;
    float4 o;
    if (ff) {
        o = ((const float4*)feat)[i4];
    } else {
        ushort4 v = ((const ushort4*)feat)[i4];
        o.x = b2f(*(const bf16*)&v.x); o.y = b2f(*(const bf16*)&v.y);
        o.z = b2f(*(const bf16*)&v.z); o.w = b2f(*(const bf16*)&v.w);
    }
    o.x = sane0(o.x); o.y = sane0(o.y); o.z = sane0(o.z); o.w = sane0(o.w);
    ((float4*)dst)[i4] = o;
}

// K4b: output 1 (feat_indices, bf16-rounded f32)
__global__ void k_aux(const int* __restrict__ fidx, float* __restrict__ out) {
    int j = blockIdx.x * 256 + threadIdx.x;  // 0..8191
    float r = b2f(__float2bfloat16((float)fidx[j]));
    out[OUT1_OFF + j] = (r == r) ? r : 0.f;
}

// K4c: fused scatter at selected pixels (after k_cvt); reads exact out2.
__global__ void k_fuse(const void* __restrict__ feat, const void* __restrict__ refs,
                       const void* __restrict__ sim, const int* __restrict__ fidx,
                       const int* __restrict__ pindex, const int* __restrict__ flags,
                       float* __restrict__ out) {
    int ff = flags[0], rf = flags[1], sf = flags[2];
    int bq = blockIdx.x;
    int b = bq >> 10;
    int q = bq & 1023;
    int c = threadIdx.x;  // 0..127
    int index = *pindex & 7;
    int idx = fidx[b * QQ + q] & (HW - 1);
    float base = ldv(sim, b * NTOT + index, sf);
    float f = ldv(feat, ((size_t)(b * CC) + c) * HW + idx, ff);
    float s = 0.f;
    const float* ridxf = out + OUT2_OFF;
    #pragma unroll
    for (int n = 0; n < NREF; n++) {
        int kn = n < index ? n : n + 1;
        float sn = ldv(sim, b * NTOT + kn, sf);
        int rk = (int)ridxf[(size_t)(b * NREF + n) * QQ + q] & (HW - 1);
        float rv = ldv(refs, ((size_t)((b * NTOT + kn) * CC) + c) * HW + rk, rf);
        s = fmaf(sn, rv, s);
    }
    out[((size_t)(b * CC) + c) * HW + idx] = sane0(base * f + s);
}

// K4d: quantize out2 in place (bf16-rounded, matching the quantized reference)
__global__ void k_round(float* __restrict__ out) {
    int j = blockIdx.x * 256 + threadIdx.x;  // 0..57343
    float v = out[OUT2_OFF + j];
    float r = b2f(__float2bfloat16(v));
    out[OUT2_OFF + j] = (r == r && fabsf(r) < 1e6f) ? r : 0.f;
}

// ---------------------------------------------------------------------------
extern "C" void kernel_launch(void* const* d_in, const int* in_sizes, int n_in,
                              void* d_out, int out_size, void* d_ws, size_t ws_size,
                              hipStream_t stream) {
    // Bind pointers by size signature, not position.
    const void* feat = 0; const void* refs = 0; const void* sim = 0;
    const int* fidx = 0; const int* pindex = 0;
    for (int i = 0; i < n_in; i++) {
        switch (in_sizes[i]) {
            case BB * CC * HW:        feat = d_in[i]; break;               // 4194304
            case BB * NTOT * CC * HW: refs = d_in[i]; break;               // 33554432
            case BB * NTOT:           sim = d_in[i]; break;                // 64
            case BB * QQ:             fidx = (const int*)d_in[i]; break;   // 8192
            case 1:                   pindex = (const int*)d_in[i]; break;
        }
    }
    float* out = (float*)d_out;
    char* ws = (char*)d_ws;
    int* flags = (int*)ws;                                       // 16 B (pad 256)
    float* wfs_t = (float*)(ws + 256);                           // 4 MiB
    float* rinv = (float*)(ws + 256 + (size_t)BB * CC * QQ * 4);         // 896 KiB
    // pairs scratch lives at the start of out0 (overwritten later by k_cvt)
    float2* pairs = (float2*)out;                                // 7.3 MiB
    float* out2 = out + OUT2_OFF;

    k_detect<<<1, 64, 0, stream>>>(feat, refs, sim, flags);
    k_wfs<<<BB * QQ, 64, 0, stream>>>(feat, fidx, flags, wfs_t);
    k_rnorm<<<BB * NREF * (HW / 256), 256, 0, stream>>>(refs, pindex, flags, rinv);
    k_argmax<<<NSPLIT * BB * NREF * 8, 256, 0, stream>>>(refs, wfs_t, rinv, pindex, flags, pairs);
    k_amax2<<<BNQ / 256, 256, 0, stream>>>(pairs, out2);
    k_cvt<<<(BB * CC * HW / 4) / 256, 256, 0, stream>>>(feat, flags, out);
    k_aux<<<(BB * QQ) / 256, 256, 0, stream>>>(fidx, out);
    k_fuse<<<BB * QQ, 128, 0, stream>>>(feat, refs, sim, fidx, pindex, flags, out);
    k_round<<<(BB * NREF * QQ) / 256, 256, 0, stream>>>(out);
}

// Round 18
// 931.087 us; speedup vs baseline: 1.6102x; 1.1247x over previous
//
#include <hip/hip_runtime.h>
#include <hip/hip_bf16.h>

#define BB 8
#define NTOT 8
#define NREF 7
#define CC 128
#define HW 4096
#define QQ 1024
#define EPSV 1e-12f
#define NSPLIT 8
#define BNQ (BB * NREF * QQ)   // 57344

// d_out layout (f32 words):
//   out0 [0, 4194304)       : fused feature map (b,c,hw)
//   out1 [4194304, 4202496) : feat_indices (bf16-rounded f32)
//   out2 [4202496, 4259840) : ref_idx (exact ints until k_round quantizes)
// Transient scratch inside out0 (overwritten later by k_cvt):
//   pairs = out words [0, NSPLIT*BNQ*2) : per-split (best,idx) float2
#define OUT1_OFF ((size_t)BB * CC * HW)
#define OUT2_OFF (OUT1_OFF + (size_t)BB * QQ)

typedef __hip_bfloat16 bf16;

__device__ __forceinline__ float b2f(bf16 v) { return __bfloat162float(v); }
__device__ __forceinline__ float sane0(float x) {
    return (x == x && fabsf(x) < 60.f) ? x : 0.f;
}
// dtype-flag-aware load: element i of a logically-float tensor
__device__ __forceinline__ float ldv(const void* p, size_t i, int f32) {
    return f32 ? ((const float*)p)[i] : b2f(((const bf16*)p)[i]);
}

// ---------------------------------------------------------------------------
// K0: detect per-tensor device dtype (f32 vs bf16). (Working since R8.)
__global__ void k_detect(const void* __restrict__ feat, const void* __restrict__ refs,
                         const void* __restrict__ sim, int* __restrict__ flags) {
    if (threadIdx.x == 0) {
        const ushort* p = (const ushort*)feat;
        int c1 = 0;
        for (int i = 0; i < 256; i++) {
            float v = b2f(*(const bf16*)&p[(size_t)i * 16384]);  // even idx
            if (!(fabsf(v) <= 100.f)) c1++;
        }
        flags[0] = c1 > 32 ? 1 : 0;
        p = (const ushort*)refs; c1 = 0;
        for (int i = 0; i < 256; i++) {
            float v = b2f(*(const bf16*)&p[(size_t)i * 131072]);
            if (!(fabsf(v) <= 100.f)) c1++;
        }
        flags[1] = c1 > 32 ? 1 : 0;
        p = (const ushort*)sim; c1 = 0;
        for (int i = 0; i < 32; i++) {
            float v = b2f(*(const bf16*)&p[i * 2]);
            if (!(fabsf(v) <= 100.f)) c1++;
        }
        flags[2] = c1 > 4 ? 1 : 0;
    }
}

// ---------------------------------------------------------------------------
// K1: per (b,q) selected feat column: l2norm over c twice -> wfs_t[b][c][q].
__global__ void k_wfs(const void* __restrict__ feat, const int* __restrict__ fidx,
                      const int* __restrict__ flags, float* __restrict__ wfs_t) {
    int ff = flags[0];
    int bq = blockIdx.x;
    int b = bq >> 10;
    int q = bq & 1023;
    int idx = fidx[b * QQ + q] & (HW - 1);
    int l = threadIdx.x;  // 0..63
    size_t base = (size_t)b * CC * HW + idx;
    float x0 = ldv(feat, base + (size_t)l * HW, ff);
    float x1 = ldv(feat, base + (size_t)(l + 64) * HW, ff);
    float s = x0 * x0 + x1 * x1;
    #pragma unroll
    for (int m = 1; m < 64; m <<= 1) s += __shfl_xor(s, m, 64);
    float d1 = fmaxf(sqrtf(s), EPSV);
    float y0 = x0 / d1, y1 = x1 / d1;
    float s2 = y0 * y0 + y1 * y1;
    #pragma unroll
    for (int m = 1; m < 64; m <<= 1) s2 += __shfl_xor(s2, m, 64);
    float d2 = fmaxf(sqrtf(s2), EPSV);
    wfs_t[((size_t)(b * CC + l)) * QQ + q] = y0 / d2;
    wfs_t[((size_t)(b * CC + l + 64)) * QQ + q] = y1 / d2;
}

// ---------------------------------------------------------------------------
// K2: rinv[b][n][k] = 1 / max(||refs col||, eps)   (one IEEE div)
__global__ void k_rnorm(const void* __restrict__ refs, const int* __restrict__ pindex,
                        const int* __restrict__ flags, float* __restrict__ rinv) {
    int rf = flags[1];
    int gb = blockIdx.x;           // B*NREF*16
    int kc = gb & 15;
    int bn = gb >> 4;
    int n = bn % NREF;
    int b = bn / NREF;
    int index = *pindex & 7;
    int kn = n < index ? n : n + 1;
    int k = kc * 256 + threadIdx.x;
    size_t base = (size_t)(b * NTOT + kn) * CC * HW + k;
    float s = 0.f;
    #pragma unroll 4
    for (int c = 0; c < CC; c++) {
        float x = ldv(refs, base + (size_t)c * HW, rf);
        s = fmaf(x, x, s);
    }
    rinv[(b * NREF + n) * HW + k] = 1.0f / fmaxf(sqrtf(s), EPSV);
}

// ---------------------------------------------------------------------------
// K3 (NSPLIT=8, the measured optimum): 8q x 8k micro-tile, vector staging,
// rinv mul, no divides in the hot loop.
__global__ __launch_bounds__(256, 4) void k_argmax(
        const void* __restrict__ refs, const float* __restrict__ wfs_t,
        const float* __restrict__ rinv, const int* __restrict__ pindex,
        const int* __restrict__ flags, float2* __restrict__ pairs) {
    __shared__ __align__(16) float lw[32][128];  // [c][q] 16 KiB
    __shared__ __align__(16) float lr[32][128];  // [c][k] 16 KiB
    int rf = flags[1];
    int gb = blockIdx.x;           // NSPLIT * 448
    int qtile = gb & 7;
    int r = gb >> 3;               // 0..NSPLIT*56-1
    int bn = r % 56;
    int ks = r / 56;
    int n = bn % NREF;
    int b = bn / NREF;
    int index = *pindex & 7;
    int kn = n < index ? n : n + 1;
    int q0 = qtile * 128;
    int kbase = ks * (HW / NSPLIT);
    int t = threadIdx.x;
    int qt = t >> 4, kt = t & 15;

    const float* wsrc = wfs_t + (size_t)b * CC * QQ + q0;
    size_t rbase = (size_t)(b * NTOT + kn) * CC * HW;
    const float* rib = rinv + (b * NREF + n) * HW;

    float best[8];
    int bidx[8];
    #pragma unroll
    for (int j = 0; j < 8; j++) { best[j] = -3.402823466e38f; bidx[j] = 0; }

    int x0 = (t & 31) * 4;    // staged k-quad within the 128-k tile
    int cb = t >> 5;          // 0..7

    for (int kt0 = 0; kt0 < HW / NSPLIT; kt0 += 128) {   // 4 k-tiles
        int k0 = kbase + kt0;
        float acc[8][8];
        #pragma unroll
        for (int j = 0; j < 8; j++)
            #pragma unroll
            for (int i = 0; i < 8; i++) acc[j][i] = 0.f;

        float4 ri4 = *(const float4*)&rib[k0 + x0];

        for (int cc0 = 0; cc0 < CC; cc0 += 32) {  // 4 c-chunks, ascending
            __syncthreads();  // previous phase's reads done
            // stage lw: 16 f32/thread, vectorized
            #pragma unroll
            for (int i = 0; i < 4; i++) {
                int flat4 = i * 1024 + t * 4;
                int c = flat4 >> 7, x = flat4 & 127;
                *(float4*)&lw[c][x] =
                    *(const float4*)&wsrc[(size_t)(cc0 + c) * QQ + x];
            }
            // stage lr: 4 k-quads x 4 c-rows per thread, scaled by rinv
            #pragma unroll
            for (int s = 0; s < 4; s++) {
                int c = cb + s * 8;      // 0..31
                float4 v;
                if (rf) {
                    v = *(const float4*)&((const float*)refs)
                            [rbase + (size_t)(cc0 + c) * HW + k0 + x0];
                } else {
                    ushort4 u = *(const ushort4*)&((const ushort*)refs)
                            [rbase + (size_t)(cc0 + c) * HW + k0 + x0];
                    v.x = b2f(*(const bf16*)&u.x); v.y = b2f(*(const bf16*)&u.y);
                    v.z = b2f(*(const bf16*)&u.z); v.w = b2f(*(const bf16*)&u.w);
                }
                v.x *= ri4.x; v.y *= ri4.y; v.z *= ri4.z; v.w *= ri4.w;
                *(float4*)&lr[c][x0] = v;
            }
            __syncthreads();

            #pragma unroll 4
            for (int c = 0; c < 32; c++) {
                const float4 wq0 = *(const float4*)&lw[c][qt * 8];
                const float4 wq1 = *(const float4*)&lw[c][qt * 8 + 4];
                const float4 rk0 = *(const float4*)&lr[c][kt * 4];
                const float4 rk1 = *(const float4*)&lr[c][64 + kt * 4];
                const float wq[8] = {wq0.x, wq0.y, wq0.z, wq0.w,
                                     wq1.x, wq1.y, wq1.z, wq1.w};
                const float rk[8] = {rk0.x, rk0.y, rk0.z, rk0.w,
                                     rk1.x, rk1.y, rk1.z, rk1.w};
                #pragma unroll
                for (int j = 0; j < 8; j++)
                    #pragma unroll
                    for (int i = 0; i < 8; i++)
                        acc[j][i] = fmaf(wq[j], rk[i], acc[j][i]);
            }
        }

        // fold this tile (ascending k order preserved)
        #pragma unroll
        for (int j = 0; j < 8; j++) {
            #pragma unroll
            for (int i = 0; i < 8; i++) {
                float v = acc[j][i];
                int gk = k0 + (i < 4 ? kt * 4 + i : 64 + kt * 4 + (i - 4));
                if (v > best[j]) { best[j] = v; bidx[j] = gk; }
            }
        }
    }

    // reduce across the 16 kt-lanes (xor 1,2,4,8 stays in the 16-lane group)
    #pragma unroll
    for (int j = 0; j < 8; j++) {
        float v = best[j];
        int i = bidx[j];
        #pragma unroll
        for (int m = 1; m < 16; m <<= 1) {
            float vo = __shfl_xor(v, m, 64);
            int io = __shfl_xor(i, m, 64);
            if (vo > v || (vo == v && io < i)) { v = vo; i = io; }
        }
        if (kt == 0) {
            float2 pr; pr.x = v; pr.y = (float)i;
            pairs[(size_t)ks * BNQ + (size_t)(b * NREF + n) * QQ + q0 + qt * 8 + j] = pr;
        }
    }
}

// K3b: fold the NSPLIT partials (ascending split order keeps first-index ties)
__global__ void k_amax2(const float2* __restrict__ pairs, float* __restrict__ out2) {
    int j = blockIdx.x * 256 + threadIdx.x;  // 0..BNQ-1
    float2 best = pairs[j];
    #pragma unroll
    for (int s = 1; s < NSPLIT; s++) {
        float2 p = pairs[(size_t)s * BNQ + j];
        if (p.x > best.x) best = p;
    }
    out2[j] = best.y;
}

// ---------------------------------------------------------------------------
// K4a: out0 background = f32(feat), dtype-aware, scrubbed. Runs AFTER k_amax2
// (overwrites the pairs scratch living at the start of out0).
__global__ void k_cvt(const void* __restrict__ feat, const int* __restrict__ flags,
                      float* __restrict__ dst) {
    int ff = flags[0];
    size_t i4 = (size_t)blockIdx.x * 256 + threadIdx.x;
    float4 o;
    if (ff) {
        o = ((const float4*)feat)[i4];
    } else {
        ushort4 v = ((const ushort4*)feat)[i4];
        o.x = b2f(*(const bf16*)&v.x); o.y = b2f(*(const bf16*)&v.y);
        o.z = b2f(*(const bf16*)&v.z); o.w = b2f(*(const bf16*)&v.w);
    }
    o.x = sane0(o.x); o.y = sane0(o.y); o.z = sane0(o.z); o.w = sane0(o.w);
    ((float4*)dst)[i4] = o;
}

// K4b: output 1 (feat_indices, bf16-rounded f32)
__global__ void k_aux(const int* __restrict__ fidx, float* __restrict__ out) {
    int j = blockIdx.x * 256 + threadIdx.x;  // 0..8191
    float r = b2f(__float2bfloat16((float)fidx[j]));
    out[OUT1_OFF + j] = (r == r) ? r : 0.f;
}

// K4c: fused scatter at selected pixels (after k_cvt); reads exact out2.
__global__ void k_fuse(const void* __restrict__ feat, const void* __restrict__ refs,
                       const void* __restrict__ sim, const int* __restrict__ fidx,
                       const int* __restrict__ pindex, const int* __restrict__ flags,
                       float* __restrict__ out) {
    int ff = flags[0], rf = flags[1], sf = flags[2];
    int bq = blockIdx.x;
    int b = bq >> 10;
    int q = bq & 1023;
    int c = threadIdx.x;  // 0..127
    int index = *pindex & 7;
    int idx = fidx[b * QQ + q] & (HW - 1);
    float base = ldv(sim, b * NTOT + index, sf);
    float f = ldv(feat, ((size_t)(b * CC) + c) * HW + idx, ff);
    float s = 0.f;
    const float* ridxf = out + OUT2_OFF;
    #pragma unroll
    for (int n = 0; n < NREF; n++) {
        int kn = n < index ? n : n + 1;
        float sn = ldv(sim, b * NTOT + kn, sf);
        int rk = (int)ridxf[(size_t)(b * NREF + n) * QQ + q] & (HW - 1);
        float rv = ldv(refs, ((size_t)((b * NTOT + kn) * CC) + c) * HW + rk, rf);
        s = fmaf(sn, rv, s);
    }
    out[((size_t)(b * CC) + c) * HW + idx] = sane0(base * f + s);
}

// K4d: quantize out2 in place (bf16-rounded, matching the quantized reference)
__global__ void k_round(float* __restrict__ out) {
    int j = blockIdx.x * 256 + threadIdx.x;  // 0..57343
    float v = out[OUT2_OFF + j];
    float r = b2f(__float2bfloat16(v));
    out[OUT2_OFF + j] = (r == r && fabsf(r) < 1e6f) ? r : 0.f;
}

// ---------------------------------------------------------------------------
extern "C" void kernel_launch(void* const* d_in, const int* in_sizes, int n_in,
                              void* d_out, int out_size, void* d_ws, size_t ws_size,
                              hipStream_t stream) {
    // Bind pointers by size signature, not position.
    const void* feat = 0; const void* refs = 0; const void* sim = 0;
    const int* fidx = 0; const int* pindex = 0;
    for (int i = 0; i < n_in; i++) {
        switch (in_sizes[i]) {
            case BB * CC * HW:        feat = d_in[i]; break;               // 4194304
            case BB * NTOT * CC * HW: refs = d_in[i]; break;               // 33554432
            case BB * NTOT:           sim = d_in[i]; break;                // 64
            case BB * QQ:             fidx = (const int*)d_in[i]; break;   // 8192
            case 1:                   pindex = (const int*)d_in[i]; break;
        }
    }
    float* out = (float*)d_out;
    char* ws = (char*)d_ws;
    int* flags = (int*)ws;                                       // 16 B (pad 256)
    float* wfs_t = (float*)(ws + 256);                           // 4 MiB
    float* rinv = (float*)(ws + 256 + (size_t)BB * CC * QQ * 4);         // 896 KiB
    // pairs scratch lives at the start of out0 (overwritten later by k_cvt)
    float2* pairs = (float2*)out;                                // 3.5 MiB
    float* out2 = out + OUT2_OFF;

    k_detect<<<1, 64, 0, stream>>>(feat, refs, sim, flags);
    k_wfs<<<BB * QQ, 64, 0, stream>>>(feat, fidx, flags, wfs_t);
    k_rnorm<<<BB * NREF * (HW / 256), 256, 0, stream>>>(refs, pindex, flags, rinv);
    k_argmax<<<NSPLIT * BB * NREF * 8, 256, 0, stream>>>(refs, wfs_t, rinv, pindex, flags, pairs);
    k_amax2<<<BNQ / 256, 256, 0, stream>>>(pairs, out2);
    k_cvt<<<(BB * CC * HW / 4) / 256, 256, 0, stream>>>(feat, flags, out);
    k_aux<<<(BB * QQ) / 256, 256, 0, stream>>>(fidx, out);
    k_fuse<<<BB * QQ, 128, 0, stream>>>(feat, refs, sim, fidx, pindex, flags, out);
    k_round<<<(BB * NREF * QQ) / 256, 256, 0, stream>>>(out);
}